// Round 5
// baseline (250.061 us; speedup 1.0000x reference)
//
#include <hip/hip_runtime.h>
#include <stdint.h>

#define B_   16384
#define D_   512
#define N1_  1024   // 2D
#define K1_  512    // D
#define N2_  512
#define K2_  1024

#define DELTA     4e-3f
#define LIST_CAP  (1u << 21)   // global list: 2M entries, 8 MB
#define LCAP      1024u        // per-block LDS list (expected ~52 hits/block)

typedef _Float16 f16x8 __attribute__((ext_vector_type(8)));
typedef float    f32x4 __attribute__((ext_vector_type(4)));

__device__ __forceinline__ void gl_lds16(const void* g, void* l) {
  __builtin_amdgcn_global_load_lds(
      (const __attribute__((address_space(1))) uint32_t*)g,
      (__attribute__((address_space(3))) uint32_t*)l, 16, 0, 0);
}

// ---------------- fused prep: convert z + weights + biases + cvec ----------------
// blk <  8192        : z -> zh fp16 (x16), zero dlogp + counter
// blk <  8192+2048   : W1 -> w1h (x64)
// blk <  8192+4096   : W2 -> w2h
// blk <  8192+4100   : biases
// else (256 blocks)  : cvec
__global__ __launch_bounds__(256) void prep_conv(const float* __restrict__ z,
                                                 const float* __restrict__ t,
                                                 const float* __restrict__ W1,
                                                 const float* __restrict__ b1,
                                                 const float* __restrict__ W2,
                                                 const float* __restrict__ b2,
                                                 _Float16* __restrict__ zh,
                                                 _Float16* __restrict__ w1h,
                                                 _Float16* __restrict__ w2h,
                                                 float* __restrict__ bias1,
                                                 float* __restrict__ bias2,
                                                 float* __restrict__ cvec,
                                                 float* __restrict__ dlogp,
                                                 uint32_t* __restrict__ counter) {
  int blk = blockIdx.x, tid = threadIdx.x;
  if (blk < 8192) {                                 // convert z
    int i = blk * 256 + tid;                        // quad index, 2097152 total
    if (blk < 64) dlogp[i] = 0.f;                   // 16384 floats
    if (i == 16384) *counter = 0;
    float4 v = ((const float4*)z)[i];
    union { _Float16 h[4]; ushort4 u; } H;
    H.h[0] = (_Float16)(v.x * 16.f);
    H.h[1] = (_Float16)(v.y * 16.f);
    H.h[2] = (_Float16)(v.z * 16.f);
    H.h[3] = (_Float16)(v.w * 16.f);
    ((ushort4*)zh)[i] = H.u;
  } else if (blk < 8192 + 2048) {                   // W1 -> w1h (1024x512 fp16, x64)
    int idx = (blk - 8192) * 256 + tid;             // [0, 524288)
    int j = idx >> 9, k = idx & 511;
    w1h[idx] = (_Float16)(W1[(size_t)j * 513 + k] * 64.f);
  } else if (blk < 8192 + 4096) {                   // W2 -> w2h (512x1024 fp16)
    int idx = (blk - 8192 - 2048) * 256 + tid;      // [0, 524288)
    int i = idx >> 10, j = idx & 1023;
    w2h[idx] = (_Float16)W2[(size_t)i * 1025 + j];
  } else if (blk < 8192 + 4100) {                   // biases
    int j = (blk - 8192 - 4096) * 256 + tid;        // [0, 1024)
    float t0 = t[0];
    bias1[j] = b1[j] + t0 * W1[(size_t)j * 513 + 512];
    if (j < 512) bias2[j] = b2[j] + t0 * W2[(size_t)j * 1025 + 1024];
  } else {                                          // c[j] = sum_k W2[k,j]*W1[j,k]
    int wave = tid >> 6, lane = tid & 63;
    int j = (blk - 8192 - 4100) * 4 + wave;         // [0, 1024)
    float s = 0.f;
    #pragma unroll
    for (int kk = 0; kk < 8; ++kk) {
      int k = lane + kk * 64;
      s += W2[(size_t)k * 1025 + j] * W1[(size_t)j * 513 + k];
    }
    #pragma unroll
    for (int off = 32; off > 0; off >>= 1) s += __shfl_xor(s, off);
    if (lane == 0) cvec[j] = s;
  }
}

// ---------------- GEMM1: h_pre = z@W1z^T, h + trace + borderline list ----------------
// Two BK=32 staging buffer pairs per iteration -> 32 MFMA/wave per barrier pair.

__global__ __launch_bounds__(256, 4)
void gemm1_kernel(const _Float16* __restrict__ zh, const _Float16* __restrict__ w1h,
                  const float* __restrict__ bias1, const float* __restrict__ cvec,
                  _Float16* __restrict__ hOut, float* __restrict__ dlogp,
                  uint32_t* __restrict__ list, uint32_t* __restrict__ counter) {
  __shared__ __align__(16) char smem[32768];   // staging 4x8K, unioned with 32K hbuf
  __shared__ uint32_t llist[LCAP];
  __shared__ uint32_t lcnt, lbase;
  _Float16* Ah0  = (_Float16*)smem;             // 128x32, k-slice 0
  _Float16* Ah1  = (_Float16*)(smem + 8192);    // 128x32, k-slice 1
  _Float16* Bh0  = (_Float16*)(smem + 16384);
  _Float16* Bh1  = (_Float16*)(smem + 24576);
  _Float16* hbuf = (_Float16*)smem;             // 128x128 (after K-loop)

  const int tid = threadIdx.x;
  const int lane = tid & 63, wave = tid >> 6;
  const int wm = wave >> 1, wn = wave & 1;
  const int q = lane >> 4, m16 = lane & 15;
  // XCD-aware swizzle: bm fastest -> the 8 bn-siblings of a bm share id%8 -> same XCD
  const int bm = blockIdx.x & 127, bn = blockIdx.x >> 7;

  if (tid == 0) lcnt = 0;

  const int c0 = tid, c1 = 256 + tid;
  const int r0 = c0 >> 2, kc0 = (c0 & 3) << 3;
  const int r1 = c1 >> 2, kc1 = (c1 & 3) << 3;
  const _Float16* zh0 = zh + (size_t)(bm * 128 + r0) * K1_ + kc0;
  const _Float16* zh1 = zh + (size_t)(bm * 128 + r1) * K1_ + kc1;
  const _Float16* wh0 = w1h + (size_t)(bn * 128 + r0) * K1_ + kc0;
  const _Float16* wh1 = w1h + (size_t)(bn * 128 + r1) * K1_ + kc1;

  f32x4 acc[4][4] = {};

  for (int k0 = 0; k0 < K1_; k0 += 64) {
    gl_lds16(zh0 + k0,      &Ah0[c0 * 8]);
    gl_lds16(zh1 + k0,      &Ah0[c1 * 8]);
    gl_lds16(zh0 + k0 + 32, &Ah1[c0 * 8]);
    gl_lds16(zh1 + k0 + 32, &Ah1[c1 * 8]);
    gl_lds16(wh0 + k0,      &Bh0[c0 * 8]);
    gl_lds16(wh1 + k0,      &Bh0[c1 * 8]);
    gl_lds16(wh0 + k0 + 32, &Bh1[c0 * 8]);
    gl_lds16(wh1 + k0 + 32, &Bh1[c1 * 8]);
    __syncthreads();
    {
      f16x8 ah[4], bh[4];
      #pragma unroll
      for (int mt = 0; mt < 4; ++mt)
        ah[mt] = *(const f16x8*)&Ah0[(wm * 64 + mt * 16 + m16) * 32 + q * 8];
      #pragma unroll
      for (int nt = 0; nt < 4; ++nt)
        bh[nt] = *(const f16x8*)&Bh0[(wn * 64 + nt * 16 + m16) * 32 + q * 8];
      #pragma unroll
      for (int mt = 0; mt < 4; ++mt)
        #pragma unroll
        for (int nt = 0; nt < 4; ++nt)
          acc[mt][nt] = __builtin_amdgcn_mfma_f32_16x16x32_f16(ah[mt], bh[nt], acc[mt][nt], 0, 0, 0);
    }
    {
      f16x8 ah[4], bh[4];
      #pragma unroll
      for (int mt = 0; mt < 4; ++mt)
        ah[mt] = *(const f16x8*)&Ah1[(wm * 64 + mt * 16 + m16) * 32 + q * 8];
      #pragma unroll
      for (int nt = 0; nt < 4; ++nt)
        bh[nt] = *(const f16x8*)&Bh1[(wn * 64 + nt * 16 + m16) * 32 + q * 8];
      #pragma unroll
      for (int mt = 0; mt < 4; ++mt)
        #pragma unroll
        for (int nt = 0; nt < 4; ++nt)
          acc[mt][nt] = __builtin_amdgcn_mfma_f32_16x16x32_f16(ah[mt], bh[nt], acc[mt][nt], 0, 0, 0);
    }
    __syncthreads();
  }

  // epilogue: hp = acc/1024 + bias1; h -> LDS hbuf; trace += mask*c; borderline -> LDS list
  float tr[16];
  #pragma unroll
  for (int i = 0; i < 16; ++i) tr[i] = 0.f;
  #pragma unroll
  for (int nt = 0; nt < 4; ++nt) {
    int coll = wn * 64 + nt * 16 + m16;          // local col
    int col = bn * 128 + coll;
    float cj = cvec[col];
    float bj = bias1[col];
    #pragma unroll
    for (int mt = 0; mt < 4; ++mt) {
      int rowl = wm * 64 + mt * 16 + q * 4;      // local row
      #pragma unroll
      for (int r = 0; r < 4; ++r) {
        float hp = acc[mt][nt][r] * (1.f / 1024.f) + bj;
        float h = hp > 0.f ? hp : 0.f;
        hbuf[(rowl + r) * 128 + coll] = (_Float16)h;
        if (hp > 0.f) tr[mt * 4 + r] += cj;
        if (__builtin_fabsf(hp) < DELTA) {
          uint32_t i = atomicAdd(&lcnt, 1u);     // LDS atomic: per-CU, cheap
          if (i < LCAP)
            llist[i] = ((uint32_t)(bm * 128 + rowl + r) << 10) | (uint32_t)col |
                       (hp > 0.f ? 0x80000000u : 0u);
        }
      }
    }
  }
  #pragma unroll
  for (int off = 1; off < 16; off <<= 1)
    #pragma unroll
    for (int i = 0; i < 16; ++i) tr[i] += __shfl_xor(tr[i], off);
  if (m16 == 0) {
    #pragma unroll
    for (int mt = 0; mt < 4; ++mt)
      #pragma unroll
      for (int r = 0; r < 4; ++r)
        atomicAdd(&dlogp[bm * 128 + wm * 64 + mt * 16 + q * 4 + r], -tr[mt * 4 + r]);
  }

  __syncthreads();
  // coalesced h store: 16B/lane, 8 iterations
  #pragma unroll
  for (int it = 0; it < 8; ++it) {
    int idx = it * 256 + tid;                    // 0..2047
    int row = idx >> 4, cc = idx & 15;
    *(uint4*)&hOut[(size_t)(bm * 128 + row) * N1_ + bn * 128 + cc * 8] =
        *(const uint4*)&hbuf[row * 128 + cc * 8];
  }

  // flush block-local list: ONE device atomic per block
  if (tid == 0) {
    uint32_t n = lcnt < LCAP ? lcnt : LCAP;
    lbase = atomicAdd(counter, n);
  }
  __syncthreads();
  uint32_t n = lcnt < LCAP ? lcnt : LCAP;
  uint32_t base = lbase;
  for (uint32_t i = tid; i < n; i += 256) {
    uint32_t gi = base + i;
    if (gi < LIST_CAP) list[gi] = llist[i];
  }
}

// ---------------- GEMM2 (+ fixup partition): dz = h@W2h^T + bias2 ----------------
// blocks [0,512): gemm2 tiles; blocks [512,640): fp32 fixup of borderline h_pre.

__global__ __launch_bounds__(256, 4)
void gemm2_kernel(const _Float16* __restrict__ h, const _Float16* __restrict__ w2,
                  const float* __restrict__ bias2, float* __restrict__ out,
                  const float* __restrict__ z, const float* __restrict__ W1,
                  const float* __restrict__ bias1, const float* __restrict__ cvec,
                  const uint32_t* __restrict__ list, const uint32_t* __restrict__ counter,
                  float* __restrict__ dlogp) {
  __shared__ __align__(16) char smem[34048];   // staging 4x8K; unioned with 64x132 f32 sbuf

  if (blockIdx.x >= 512) {                     // ---- fixup partition ----
    uint32_t cnt = *counter;
    if (cnt > LIST_CAP) cnt = LIST_CAP;
    const int wid = ((blockIdx.x - 512) * 256 + threadIdx.x) >> 6;
    const int lane = threadIdx.x & 63;
    const int nw = 128 * 4;
    for (uint32_t i = wid; i < cnt; i += nw) {
      uint32_t e = list[i];
      int row = (int)((e >> 10) & 16383u);
      int col = (int)(e & 1023u);
      int oldm = (int)(e >> 31);
      float s = 0.f;
      #pragma unroll
      for (int it = 0; it < 8; ++it) {
        int k = it * 64 + lane;
        s += z[(size_t)row * 512 + k] * W1[(size_t)col * 513 + k];
      }
      #pragma unroll
      for (int off = 32; off > 0; off >>= 1) s += __shfl_xor(s, off);
      if (lane == 0) {
        float hp = s + bias1[col];
        int newm = hp > 0.f ? 1 : 0;
        if (newm != oldm)
          atomicAdd(&dlogp[row], oldm ? cvec[col] : -cvec[col]);
      }
    }
    return;
  }

  _Float16* As0 = (_Float16*)smem;
  _Float16* As1 = (_Float16*)(smem + 8192);
  _Float16* Bs0 = (_Float16*)(smem + 16384);
  _Float16* Bs1 = (_Float16*)(smem + 24576);
  float*    sbuf = (float*)smem;               // 64 x 132 f32 (after K-loop)

  const int tid = threadIdx.x;
  const int lane = tid & 63, wave = tid >> 6;
  const int wm = wave >> 1, wn = wave & 1;
  const int q = lane >> 4, m16 = lane & 15;
  const int bm = blockIdx.x & 127, bn = blockIdx.x >> 7;   // bn in [0,4)

  const int c0 = tid, c1 = 256 + tid;
  const int r0 = c0 >> 2, kc0 = (c0 & 3) << 3;
  const int r1 = c1 >> 2, kc1 = (c1 & 3) << 3;
  const _Float16* hA0 = h + (size_t)(bm * 128 + r0) * K2_ + kc0;
  const _Float16* hA1 = h + (size_t)(bm * 128 + r1) * K2_ + kc1;
  const _Float16* wB0 = w2 + (size_t)(bn * 128 + r0) * K2_ + kc0;
  const _Float16* wB1 = w2 + (size_t)(bn * 128 + r1) * K2_ + kc1;

  f32x4 acc[4][4] = {};

  for (int k0 = 0; k0 < K2_; k0 += 64) {
    gl_lds16(hA0 + k0,      &As0[c0 * 8]);
    gl_lds16(hA1 + k0,      &As0[c1 * 8]);
    gl_lds16(hA0 + k0 + 32, &As1[c0 * 8]);
    gl_lds16(hA1 + k0 + 32, &As1[c1 * 8]);
    gl_lds16(wB0 + k0,      &Bs0[c0 * 8]);
    gl_lds16(wB1 + k0,      &Bs0[c1 * 8]);
    gl_lds16(wB0 + k0 + 32, &Bs1[c0 * 8]);
    gl_lds16(wB1 + k0 + 32, &Bs1[c1 * 8]);
    __syncthreads();
    {
      f16x8 af[4], bf[4];
      #pragma unroll
      for (int mt = 0; mt < 4; ++mt)
        af[mt] = *(const f16x8*)&As0[(wm * 64 + mt * 16 + m16) * 32 + q * 8];
      #pragma unroll
      for (int nt = 0; nt < 4; ++nt)
        bf[nt] = *(const f16x8*)&Bs0[(wn * 64 + nt * 16 + m16) * 32 + q * 8];
      #pragma unroll
      for (int mt = 0; mt < 4; ++mt)
        #pragma unroll
        for (int nt = 0; nt < 4; ++nt)
          acc[mt][nt] = __builtin_amdgcn_mfma_f32_16x16x32_f16(af[mt], bf[nt], acc[mt][nt], 0, 0, 0);
    }
    {
      f16x8 af[4], bf[4];
      #pragma unroll
      for (int mt = 0; mt < 4; ++mt)
        af[mt] = *(const f16x8*)&As1[(wm * 64 + mt * 16 + m16) * 32 + q * 8];
      #pragma unroll
      for (int nt = 0; nt < 4; ++nt)
        bf[nt] = *(const f16x8*)&Bs1[(wn * 64 + nt * 16 + m16) * 32 + q * 8];
      #pragma unroll
      for (int mt = 0; mt < 4; ++mt)
        #pragma unroll
        for (int nt = 0; nt < 4; ++nt)
          acc[mt][nt] = __builtin_amdgcn_mfma_f32_16x16x32_f16(af[mt], bf[nt], acc[mt][nt], 0, 0, 0);
    }
    __syncthreads();
  }

  // epilogue: two 64-row halves, staged through LDS for coalesced 16B stores
  #pragma unroll
  for (int half = 0; half < 2; ++half) {
    if (wm == half) {
      #pragma unroll
      for (int nt = 0; nt < 4; ++nt) {
        int coll = wn * 64 + nt * 16 + m16;
        float bj = bias2[bn * 128 + coll];
        #pragma unroll
        for (int mt = 0; mt < 4; ++mt) {
          int rowl = mt * 16 + q * 4;
          #pragma unroll
          for (int r = 0; r < 4; ++r)
            sbuf[(rowl + r) * 132 + coll] = acc[mt][nt][r] + bj;
        }
      }
    }
    __syncthreads();
    #pragma unroll
    for (int it = 0; it < 8; ++it) {
      int idx = it * 256 + tid;                  // 0..2047
      int row = idx >> 5, c4 = idx & 31;         // row 0..63, 4-float col group
      *(uint4*)&out[(size_t)(bm * 128 + half * 64 + row) * N2_ + bn * 128 + c4 * 4] =
          *(const uint4*)&sbuf[row * 132 + c4 * 4];
    }
    __syncthreads();
  }
}

// ---------------- launcher ----------------

extern "C" void kernel_launch(void* const* d_in, const int* in_sizes, int n_in,
                              void* d_out, int out_size, void* d_ws, size_t ws_size,
                              hipStream_t stream) {
  const float* t  = (const float*)d_in[0];
  const float* z  = (const float*)d_in[1];
  // d_in[2] = logp_z, unused
  const float* W1 = (const float*)d_in[3];
  const float* b1 = (const float*)d_in[4];
  const float* W2 = (const float*)d_in[5];
  const float* b2 = (const float*)d_in[6];

  float* out   = (float*)d_out;
  float* dlogp = out + (size_t)B_ * D_;

  char* ws = (char*)d_ws;
  _Float16* zhp   = (_Float16*)ws; ws += (size_t)B_ * K1_ * 2;   // 16 MB
  _Float16* w1h   = (_Float16*)ws; ws += (size_t)N1_ * K1_ * 2;  // 1 MB
  _Float16* w2h   = (_Float16*)ws; ws += (size_t)N2_ * K2_ * 2;  // 1 MB
  float*    bias1 = (float*)ws;    ws += 1024 * 4;
  float*    bias2 = (float*)ws;    ws += 512 * 4;
  float*    cvec  = (float*)ws;    ws += 1024 * 4;
  uint32_t* counter = (uint32_t*)ws; ws += 256;
  uint32_t* list  = (uint32_t*)ws; ws += (size_t)LIST_CAP * 4;   // 8 MB
  _Float16* hWs   = (_Float16*)ws; ws += (size_t)B_ * N1_ * 2;   // 32 MB

  prep_conv<<<8192 + 4100 + 256, 256, 0, stream>>>(z, t, W1, b1, W2, b2, zhp, w1h, w2h,
                                                   bias1, bias2, cvec, dlogp, counter);
  gemm1_kernel<<<1024, 256, 0, stream>>>(zhp, w1h, bias1, cvec, hWs, dlogp, list, counter);
  gemm2_kernel<<<640, 256, 0, stream>>>(hWs, w2h, bias2, out,
                                        z, W1, bias1, cvec, list, counter, dlogp);
}

// Round 6
// 182.102 us; speedup vs baseline: 1.3732x; 1.3732x over previous
//
#include <hip/hip_runtime.h>
#include <stdint.h>

#define B_   16384
#define D_   512
#define N1_  1024   // 2D
#define K1_  512    // D
#define N2_  512
#define K2_  1024

#define DELTA     4e-3f
#define LIST_CAP  (1u << 21)   // global list: 2M entries, 8 MB
#define LCAP      1024u        // per-block LDS list (expected ~52 hits/block)

typedef _Float16 f16x8 __attribute__((ext_vector_type(8)));
typedef float    f32x4 __attribute__((ext_vector_type(4)));

__device__ __forceinline__ void gl_lds16(const void* g, void* l) {
  __builtin_amdgcn_global_load_lds(
      (const __attribute__((address_space(1))) uint32_t*)g,
      (__attribute__((address_space(3))) uint32_t*)l, 16, 0, 0);
}

// ---------------- fused prep: convert z + weights + biases + cvec ----------------
__global__ __launch_bounds__(256) void prep_conv(const float* __restrict__ z,
                                                 const float* __restrict__ t,
                                                 const float* __restrict__ W1,
                                                 const float* __restrict__ b1,
                                                 const float* __restrict__ W2,
                                                 const float* __restrict__ b2,
                                                 _Float16* __restrict__ zh,
                                                 _Float16* __restrict__ w1h,
                                                 _Float16* __restrict__ w2h,
                                                 float* __restrict__ bias1,
                                                 float* __restrict__ bias2,
                                                 float* __restrict__ cvec,
                                                 float* __restrict__ dlogp,
                                                 uint32_t* __restrict__ counter) {
  int blk = blockIdx.x, tid = threadIdx.x;
  if (blk < 8192) {                                 // convert z
    int i = blk * 256 + tid;                        // quad index, 2097152 total
    if (blk < 64) dlogp[i] = 0.f;                   // 16384 floats
    if (i == 16384) *counter = 0;
    float4 v = ((const float4*)z)[i];
    union { _Float16 h[4]; ushort4 u; } H;
    H.h[0] = (_Float16)(v.x * 16.f);
    H.h[1] = (_Float16)(v.y * 16.f);
    H.h[2] = (_Float16)(v.z * 16.f);
    H.h[3] = (_Float16)(v.w * 16.f);
    ((ushort4*)zh)[i] = H.u;
  } else if (blk < 8192 + 2048) {                   // W1 -> w1h (1024x512 fp16, x64)
    int idx = (blk - 8192) * 256 + tid;             // [0, 524288)
    int j = idx >> 9, k = idx & 511;
    w1h[idx] = (_Float16)(W1[(size_t)j * 513 + k] * 64.f);
  } else if (blk < 8192 + 4096) {                   // W2 -> w2h (512x1024 fp16)
    int idx = (blk - 8192 - 2048) * 256 + tid;      // [0, 524288)
    int i = idx >> 10, j = idx & 1023;
    w2h[idx] = (_Float16)W2[(size_t)i * 1025 + j];
  } else if (blk < 8192 + 4100) {                   // biases
    int j = (blk - 8192 - 4096) * 256 + tid;        // [0, 1024)
    float t0 = t[0];
    bias1[j] = b1[j] + t0 * W1[(size_t)j * 513 + 512];
    if (j < 512) bias2[j] = b2[j] + t0 * W2[(size_t)j * 1025 + 1024];
  } else {                                          // c[j] = sum_k W2[k,j]*W1[j,k]
    int wave = tid >> 6, lane = tid & 63;
    int j = (blk - 8192 - 4100) * 4 + wave;         // [0, 1024)
    float s = 0.f;
    #pragma unroll
    for (int kk = 0; kk < 8; ++kk) {
      int k = lane + kk * 64;
      s += W2[(size_t)k * 1025 + j] * W1[(size_t)j * 513 + k];
    }
    #pragma unroll
    for (int off = 32; off > 0; off >>= 1) s += __shfl_xor(s, off);
    if (lane == 0) cvec[j] = s;
  }
}

// ---------------- GEMM1: h_pre = z@W1z^T, h + trace + borderline list ----------------
// Two BK=32 staging buffer pairs per iteration -> 32 MFMA/wave per barrier pair.

__global__ __launch_bounds__(256, 4)
void gemm1_kernel(const _Float16* __restrict__ zh, const _Float16* __restrict__ w1h,
                  const float* __restrict__ bias1, const float* __restrict__ cvec,
                  _Float16* __restrict__ hOut, float* __restrict__ dlogp,
                  uint32_t* __restrict__ list, uint32_t* __restrict__ counter) {
  __shared__ __align__(16) char smem[32768];   // staging 4x8K, unioned with 32K hbuf
  __shared__ uint32_t llist[LCAP];
  __shared__ uint32_t lcnt, lbase;
  _Float16* Ah0  = (_Float16*)smem;             // 128x32, k-slice 0
  _Float16* Ah1  = (_Float16*)(smem + 8192);    // 128x32, k-slice 1
  _Float16* Bh0  = (_Float16*)(smem + 16384);
  _Float16* Bh1  = (_Float16*)(smem + 24576);
  _Float16* hbuf = (_Float16*)smem;             // 128x128 (after K-loop)

  const int tid = threadIdx.x;
  const int lane = tid & 63, wave = tid >> 6;
  const int wm = wave >> 1, wn = wave & 1;
  const int q = lane >> 4, m16 = lane & 15;
  // XCD-aware swizzle: bm fastest -> the 8 bn-siblings of a bm share id%8 -> same XCD
  const int bm = blockIdx.x & 127, bn = blockIdx.x >> 7;

  if (tid == 0) lcnt = 0;

  const int c0 = tid, c1 = 256 + tid;
  const int r0 = c0 >> 2, kc0 = (c0 & 3) << 3;
  const int r1 = c1 >> 2, kc1 = (c1 & 3) << 3;
  const _Float16* zh0 = zh + (size_t)(bm * 128 + r0) * K1_ + kc0;
  const _Float16* zh1 = zh + (size_t)(bm * 128 + r1) * K1_ + kc1;
  const _Float16* wh0 = w1h + (size_t)(bn * 128 + r0) * K1_ + kc0;
  const _Float16* wh1 = w1h + (size_t)(bn * 128 + r1) * K1_ + kc1;

  f32x4 acc[4][4] = {};

  for (int k0 = 0; k0 < K1_; k0 += 64) {
    gl_lds16(zh0 + k0,      &Ah0[c0 * 8]);
    gl_lds16(zh1 + k0,      &Ah0[c1 * 8]);
    gl_lds16(zh0 + k0 + 32, &Ah1[c0 * 8]);
    gl_lds16(zh1 + k0 + 32, &Ah1[c1 * 8]);
    gl_lds16(wh0 + k0,      &Bh0[c0 * 8]);
    gl_lds16(wh1 + k0,      &Bh0[c1 * 8]);
    gl_lds16(wh0 + k0 + 32, &Bh1[c0 * 8]);
    gl_lds16(wh1 + k0 + 32, &Bh1[c1 * 8]);
    __syncthreads();
    {
      f16x8 ah[4], bh[4];
      #pragma unroll
      for (int mt = 0; mt < 4; ++mt)
        ah[mt] = *(const f16x8*)&Ah0[(wm * 64 + mt * 16 + m16) * 32 + q * 8];
      #pragma unroll
      for (int nt = 0; nt < 4; ++nt)
        bh[nt] = *(const f16x8*)&Bh0[(wn * 64 + nt * 16 + m16) * 32 + q * 8];
      #pragma unroll
      for (int mt = 0; mt < 4; ++mt)
        #pragma unroll
        for (int nt = 0; nt < 4; ++nt)
          acc[mt][nt] = __builtin_amdgcn_mfma_f32_16x16x32_f16(ah[mt], bh[nt], acc[mt][nt], 0, 0, 0);
    }
    {
      f16x8 ah[4], bh[4];
      #pragma unroll
      for (int mt = 0; mt < 4; ++mt)
        ah[mt] = *(const f16x8*)&Ah1[(wm * 64 + mt * 16 + m16) * 32 + q * 8];
      #pragma unroll
      for (int nt = 0; nt < 4; ++nt)
        bh[nt] = *(const f16x8*)&Bh1[(wn * 64 + nt * 16 + m16) * 32 + q * 8];
      #pragma unroll
      for (int mt = 0; mt < 4; ++mt)
        #pragma unroll
        for (int nt = 0; nt < 4; ++nt)
          acc[mt][nt] = __builtin_amdgcn_mfma_f32_16x16x32_f16(ah[mt], bh[nt], acc[mt][nt], 0, 0, 0);
    }
    __syncthreads();
  }

  // epilogue: hp = acc/1024 + bias1; h -> LDS hbuf; trace += mask*c; borderline -> LDS list
  float tr[16];
  #pragma unroll
  for (int i = 0; i < 16; ++i) tr[i] = 0.f;
  #pragma unroll
  for (int nt = 0; nt < 4; ++nt) {
    int coll = wn * 64 + nt * 16 + m16;          // local col
    int col = bn * 128 + coll;
    float cj = cvec[col];
    float bj = bias1[col];
    #pragma unroll
    for (int mt = 0; mt < 4; ++mt) {
      int rowl = wm * 64 + mt * 16 + q * 4;      // local row
      #pragma unroll
      for (int r = 0; r < 4; ++r) {
        float hp = acc[mt][nt][r] * (1.f / 1024.f) + bj;
        float h = hp > 0.f ? hp : 0.f;
        hbuf[(rowl + r) * 128 + coll] = (_Float16)h;
        if (hp > 0.f) tr[mt * 4 + r] += cj;
        if (__builtin_fabsf(hp) < DELTA) {
          uint32_t i = atomicAdd(&lcnt, 1u);     // LDS atomic: per-CU, cheap
          if (i < LCAP)
            llist[i] = ((uint32_t)(bm * 128 + rowl + r) << 10) | (uint32_t)col |
                       (hp > 0.f ? 0x80000000u : 0u);
        }
      }
    }
  }
  #pragma unroll
  for (int off = 1; off < 16; off <<= 1)
    #pragma unroll
    for (int i = 0; i < 16; ++i) tr[i] += __shfl_xor(tr[i], off);
  if (m16 == 0) {
    #pragma unroll
    for (int mt = 0; mt < 4; ++mt)
      #pragma unroll
      for (int r = 0; r < 4; ++r)
        atomicAdd(&dlogp[bm * 128 + wm * 64 + mt * 16 + q * 4 + r], -tr[mt * 4 + r]);
  }

  __syncthreads();
  // coalesced h store: 16B/lane, 8 iterations
  #pragma unroll
  for (int it = 0; it < 8; ++it) {
    int idx = it * 256 + tid;                    // 0..2047
    int row = idx >> 4, cc = idx & 15;
    *(uint4*)&hOut[(size_t)(bm * 128 + row) * N1_ + bn * 128 + cc * 8] =
        *(const uint4*)&hbuf[row * 128 + cc * 8];
  }

  // flush block-local list: ONE device atomic per block
  if (tid == 0) {
    uint32_t n = lcnt < LCAP ? lcnt : LCAP;
    lbase = atomicAdd(counter, n);
  }
  __syncthreads();
  uint32_t n = lcnt < LCAP ? lcnt : LCAP;
  uint32_t base = lbase;
  for (uint32_t i = tid; i < n; i += 256) {
    uint32_t gi = base + i;
    if (gi < LIST_CAP) list[gi] = llist[i];
  }
}

// ---------------- fixup: recompute borderline h_pre in fp32, patch dlogp ----------------
// 2048 blocks = 8192 waves -> ~6-7 entries/wave; per-entry loads independent.

__global__ __launch_bounds__(256)
void fixup_kernel(const float* __restrict__ z, const float* __restrict__ W1,
                  const float* __restrict__ bias1, const float* __restrict__ cvec,
                  const uint32_t* __restrict__ list, const uint32_t* __restrict__ counter,
                  float* __restrict__ dlogp) {
  uint32_t cnt = *counter;
  if (cnt > LIST_CAP) cnt = LIST_CAP;
  const int wid = (blockIdx.x * 256 + threadIdx.x) >> 6;
  const int lane = threadIdx.x & 63;
  const int nw = gridDim.x * 4;
  for (uint32_t i = wid; i < cnt; i += nw) {
    uint32_t e = list[i];
    int row = (int)((e >> 10) & 16383u);
    int col = (int)(e & 1023u);
    int oldm = (int)(e >> 31);
    float s = 0.f;
    #pragma unroll
    for (int it = 0; it < 8; ++it) {
      int k = it * 64 + lane;
      s += z[(size_t)row * 512 + k] * W1[(size_t)col * 513 + k];
    }
    #pragma unroll
    for (int off = 32; off > 0; off >>= 1) s += __shfl_xor(s, off);
    if (lane == 0) {
      float hp = s + bias1[col];
      int newm = hp > 0.f ? 1 : 0;
      if (newm != oldm)
        atomicAdd(&dlogp[row], oldm ? cvec[col] : -cvec[col]);
    }
  }
}

// ---------------- GEMM2: dz = h@W2h^T + bias2 ----------------

__global__ __launch_bounds__(256, 4)
void gemm2_kernel(const _Float16* __restrict__ h, const _Float16* __restrict__ w2,
                  const float* __restrict__ bias2, float* __restrict__ out) {
  __shared__ __align__(16) char smem[34048];   // staging 4x8K; unioned with 64x132 f32 sbuf
  _Float16* As0 = (_Float16*)smem;
  _Float16* As1 = (_Float16*)(smem + 8192);
  _Float16* Bs0 = (_Float16*)(smem + 16384);
  _Float16* Bs1 = (_Float16*)(smem + 24576);
  float*    sbuf = (float*)smem;               // 64 x 132 f32 (after K-loop)

  const int tid = threadIdx.x;
  const int lane = tid & 63, wave = tid >> 6;
  const int wm = wave >> 1, wn = wave & 1;
  const int q = lane >> 4, m16 = lane & 15;
  const int bm = blockIdx.x & 127, bn = blockIdx.x >> 7;   // bn in [0,4)

  const int c0 = tid, c1 = 256 + tid;
  const int r0 = c0 >> 2, kc0 = (c0 & 3) << 3;
  const int r1 = c1 >> 2, kc1 = (c1 & 3) << 3;
  const _Float16* hA0 = h + (size_t)(bm * 128 + r0) * K2_ + kc0;
  const _Float16* hA1 = h + (size_t)(bm * 128 + r1) * K2_ + kc1;
  const _Float16* wB0 = w2 + (size_t)(bn * 128 + r0) * K2_ + kc0;
  const _Float16* wB1 = w2 + (size_t)(bn * 128 + r1) * K2_ + kc1;

  f32x4 acc[4][4] = {};

  for (int k0 = 0; k0 < K2_; k0 += 64) {
    gl_lds16(hA0 + k0,      &As0[c0 * 8]);
    gl_lds16(hA1 + k0,      &As0[c1 * 8]);
    gl_lds16(hA0 + k0 + 32, &As1[c0 * 8]);
    gl_lds16(hA1 + k0 + 32, &As1[c1 * 8]);
    gl_lds16(wB0 + k0,      &Bs0[c0 * 8]);
    gl_lds16(wB1 + k0,      &Bs0[c1 * 8]);
    gl_lds16(wB0 + k0 + 32, &Bs1[c0 * 8]);
    gl_lds16(wB1 + k0 + 32, &Bs1[c1 * 8]);
    __syncthreads();
    {
      f16x8 af[4], bf[4];
      #pragma unroll
      for (int mt = 0; mt < 4; ++mt)
        af[mt] = *(const f16x8*)&As0[(wm * 64 + mt * 16 + m16) * 32 + q * 8];
      #pragma unroll
      for (int nt = 0; nt < 4; ++nt)
        bf[nt] = *(const f16x8*)&Bs0[(wn * 64 + nt * 16 + m16) * 32 + q * 8];
      #pragma unroll
      for (int mt = 0; mt < 4; ++mt)
        #pragma unroll
        for (int nt = 0; nt < 4; ++nt)
          acc[mt][nt] = __builtin_amdgcn_mfma_f32_16x16x32_f16(af[mt], bf[nt], acc[mt][nt], 0, 0, 0);
    }
    {
      f16x8 af[4], bf[4];
      #pragma unroll
      for (int mt = 0; mt < 4; ++mt)
        af[mt] = *(const f16x8*)&As1[(wm * 64 + mt * 16 + m16) * 32 + q * 8];
      #pragma unroll
      for (int nt = 0; nt < 4; ++nt)
        bf[nt] = *(const f16x8*)&Bs1[(wn * 64 + nt * 16 + m16) * 32 + q * 8];
      #pragma unroll
      for (int mt = 0; mt < 4; ++mt)
        #pragma unroll
        for (int nt = 0; nt < 4; ++nt)
          acc[mt][nt] = __builtin_amdgcn_mfma_f32_16x16x32_f16(af[mt], bf[nt], acc[mt][nt], 0, 0, 0);
    }
    __syncthreads();
  }

  // epilogue: two 64-row halves, staged through LDS for coalesced 16B stores
  #pragma unroll
  for (int half = 0; half < 2; ++half) {
    if (wm == half) {
      #pragma unroll
      for (int nt = 0; nt < 4; ++nt) {
        int coll = wn * 64 + nt * 16 + m16;
        float bj = bias2[bn * 128 + coll];
        #pragma unroll
        for (int mt = 0; mt < 4; ++mt) {
          int rowl = mt * 16 + q * 4;
          #pragma unroll
          for (int r = 0; r < 4; ++r)
            sbuf[(rowl + r) * 132 + coll] = acc[mt][nt][r] + bj;
        }
      }
    }
    __syncthreads();
    #pragma unroll
    for (int it = 0; it < 8; ++it) {
      int idx = it * 256 + tid;                  // 0..2047
      int row = idx >> 5, c4 = idx & 31;         // row 0..63, 4-float col group
      *(uint4*)&out[(size_t)(bm * 128 + half * 64 + row) * N2_ + bn * 128 + c4 * 4] =
          *(const uint4*)&sbuf[row * 132 + c4 * 4];
    }
    __syncthreads();
  }
}

// ---------------- launcher ----------------

extern "C" void kernel_launch(void* const* d_in, const int* in_sizes, int n_in,
                              void* d_out, int out_size, void* d_ws, size_t ws_size,
                              hipStream_t stream) {
  const float* t  = (const float*)d_in[0];
  const float* z  = (const float*)d_in[1];
  // d_in[2] = logp_z, unused
  const float* W1 = (const float*)d_in[3];
  const float* b1 = (const float*)d_in[4];
  const float* W2 = (const float*)d_in[5];
  const float* b2 = (const float*)d_in[6];

  float* out   = (float*)d_out;
  float* dlogp = out + (size_t)B_ * D_;

  char* ws = (char*)d_ws;
  _Float16* zhp   = (_Float16*)ws; ws += (size_t)B_ * K1_ * 2;   // 16 MB
  _Float16* w1h   = (_Float16*)ws; ws += (size_t)N1_ * K1_ * 2;  // 1 MB
  _Float16* w2h   = (_Float16*)ws; ws += (size_t)N2_ * K2_ * 2;  // 1 MB
  float*    bias1 = (float*)ws;    ws += 1024 * 4;
  float*    bias2 = (float*)ws;    ws += 512 * 4;
  float*    cvec  = (float*)ws;    ws += 1024 * 4;
  uint32_t* counter = (uint32_t*)ws; ws += 256;
  uint32_t* list  = (uint32_t*)ws; ws += (size_t)LIST_CAP * 4;   // 8 MB
  _Float16* hWs   = (_Float16*)ws; ws += (size_t)B_ * N1_ * 2;   // 32 MB

  prep_conv<<<8192 + 4100 + 256, 256, 0, stream>>>(z, t, W1, b1, W2, b2, zhp, w1h, w2h,
                                                   bias1, bias2, cvec, dlogp, counter);
  gemm1_kernel<<<1024, 256, 0, stream>>>(zhp, w1h, bias1, cvec, hWs, dlogp, list, counter);
  fixup_kernel<<<2048, 256, 0, stream>>>(z, W1, bias1, cvec, list, counter, dlogp);
  gemm2_kernel<<<512, 256, 0, stream>>>(hWs, w2h, bias2, out);
}